// Round 13
// baseline (112.538 us; speedup 1.0000x reference)
//
#include <hip/hip_runtime.h>

// GE2E loss, N=1024 spk, M=32 utt, D=512.
// v13: MX-scaled fp8 GEMM (mfma_scale_f32_32x32x64_f8f6f4, unit E8M0 scales
// = bit-identical to non-scaled fp8 but 2x the MFMA rate). prep (r11-verbatim,
// linear layout): e8 = fp8(8*emb), ck8 = fp8(16*sgn(lw)*ck). gemm: 2048 blocks
// of 128x128, 4 waves (64x64 each = 2x2 of 32x32 MFMA, K=64 per instruction);
// LDS ring of 3 x 16 KB; stage(t+2) at tile start via global_load_lds
// (pre-swizzled source, r12 0-conflict layout); ONE barrier + vmcnt(4) per
// K-tile. Fragment = 32 consecutive k-bytes/lane = 2 ds_read_b128 with the
// measured-0-conflict XOR pattern. sims scaled x128*sgn; /128 in rowred.

#define N_SPK 1024
#define M_UTT 32
#define D_DIM 512
#define NROWS (N_SPK * M_UTT)   // 32768
#define NTILES 8                // 1024/128 col tiles
#define MTILES 256              // 32768/128 row tiles
#define NWG (MTILES * NTILES)   // 2048
#define NKT 8                   // 512/64

typedef __attribute__((ext_vector_type(16))) float f32x16;
typedef __attribute__((ext_vector_type(8)))  int   i32x8;
typedef __attribute__((ext_vector_type(4)))  int   i32x4;

__device__ __forceinline__ void gload_lds16(const void* g, void* l) {
    __builtin_amdgcn_global_load_lds(
        (const __attribute__((address_space(1))) unsigned int*)g,
        (__attribute__((address_space(3))) unsigned int*)l, 16, 0, 0);
}

__device__ __forceinline__ float sigmoidf(float x) {
    return 1.f / (1.f + __expf(-x));
}

// ---- k1: e8 = fp8(8*emb), ck8 = fp8(16*sgn(lw)*ck), linear (r11) -----------
__global__ void __launch_bounds__(256) prep_kernel(const float* __restrict__ emb,
                                                   const float* __restrict__ lnw,
                                                   unsigned int* __restrict__ e8,
                                                   unsigned int* __restrict__ ck8) {
    __shared__ float part[2][D_DIM];
    const int n = blockIdx.x;
    const int t = threadIdx.x;
    const int d4 = (t & 127) * 4;
    const int mh = t >> 7;
    const float* base = emb + (size_t)n * M_UTT * D_DIM;

    float4 acc = {0.f, 0.f, 0.f, 0.f};
#pragma unroll
    for (int mm = 0; mm < 16; ++mm) {
        const int m = mh * 16 + mm;
        const float4 v = *reinterpret_cast<const float4*>(base + m * D_DIM + d4);
        acc.x += v.x; acc.y += v.y; acc.z += v.z; acc.w += v.w;
        int w = __builtin_amdgcn_cvt_pk_fp8_f32(8.f * v.x, 8.f * v.y, 0, false);
        w = __builtin_amdgcn_cvt_pk_fp8_f32(8.f * v.z, 8.f * v.w, w, true);
        e8[(((size_t)(n * M_UTT + m)) * D_DIM + d4) >> 2] = (unsigned int)w;
    }
    *reinterpret_cast<float4*>(&part[mh][d4]) = acc;
    __syncthreads();
    if (t < 128) {
        const float sgn = (lnw[0] >= 0.f) ? 1.f : -1.f;
        const float sc = sgn * 0.5f;   // 16*sgn*(sum/32)
        const int d = t * 4;
        const float4 a = *reinterpret_cast<const float4*>(&part[0][d]);
        const float4 b = *reinterpret_cast<const float4*>(&part[1][d]);
        int w = __builtin_amdgcn_cvt_pk_fp8_f32((a.x + b.x) * sc, (a.y + b.y) * sc, 0, false);
        w = __builtin_amdgcn_cvt_pk_fp8_f32((a.z + b.z) * sc, (a.w + b.w) * sc, w, true);
        ck8[(((size_t)n) * D_DIM + d) >> 2] = (unsigned int)w;
    }
}

// ---- k2: MX-fp8 GEMM, 128x128 blocks, ring-3, counted vmcnt ----------------
__global__ void __launch_bounds__(256)
gemm_kernel(const char* __restrict__ e8,
            const char* __restrict__ ck8,
            float* __restrict__ maxo_part,
            float* __restrict__ own_part) {
    // buf[slot]: A 128x64B at [0,8192), B at [8192,16384).
    // line L (128B) = rows {2L,2L+1}; logical 16B-chunk l = (row&1)*4 + c
    // (c = byte-chunk k/16), stored at phys = l ^ (L&7).
    __shared__ __align__(16) char buf[3][16384];   // 48 KB
    __shared__ float redm[2][128];
    __shared__ float redo[2][128];

    const int tid  = threadIdx.x;
    const int lane = tid & 63;
    const int wv   = tid >> 6;
    const int l31  = lane & 31;
    const int kg   = lane >> 5;    // k-half (32 bytes each)
    const int wm   = wv >> 1;      // 0..1 : 64-row half
    const int wn   = wv & 1;       // 0..1 : 64-col half

    // XCD map: xcd gets 32 consecutive mt x all 8 nt
    const int raw   = blockIdx.x;
    const int xcd   = raw & 7;
    const int local = raw >> 3;              // 0..255
    const int mt    = xcd * 32 + (local >> 3);
    const int nt    = local & 7;
    const int r0    = mt * 128;
    const int n0    = nt * 128;

    // ---- staging map (r12-verbatim): 512 16B-chunks per region, 2/thread ----
    const char* pA[2];
    const char* pB[2];
    int dA[2], dB[2];
#pragma unroll
    for (int j = 0; j < 2; ++j) {
        const int s   = j * 256 + tid;
        const int L   = s >> 3;
        const int l   = (s & 7) ^ (L & 7);
        const int row = 2 * L + (l >> 2);
        const int c   = l & 3;
        pA[j] = e8  + (size_t)(r0 + row) * D_DIM + c * 16;
        pB[j] = ck8 + (size_t)(n0 + row) * D_DIM + c * 16;
        dA[j] = s * 16;
        dB[j] = 8192 + s * 16;
    }

    auto stage = [&](int u, int slot) {
        char* bb = &buf[slot][0];
        const int ko = u * 64;
#pragma unroll
        for (int j = 0; j < 2; ++j) {
            gload_lds16(pA[j] + ko, bb + dA[j]);
            gload_lds16(pB[j] + ko, bb + dB[j]);
        }
    };

    // prologue: tiles 0,1 in flight; gate tile 0 only
    stage(0, 0);
    stage(1, 1);
    asm volatile("s_waitcnt vmcnt(4)" ::: "memory");
    __builtin_amdgcn_s_barrier();

    // ---- fragment read offsets: 32B/lane = 2 x b128, 0-conflict pattern ----
    // row r: L = r>>1, u = r&1; chunk c = kg*2 + h; byte = L*128 + ((u*4+c)^(L&7))*16
    int aoff[2][2], boff[2][2];
#pragma unroll
    for (int am = 0; am < 2; ++am) {
        const int r = wm * 64 + am * 32 + l31;
        const int L = r >> 1, u = r & 1, s = L & 7;
#pragma unroll
        for (int h = 0; h < 2; ++h)
            aoff[am][h] = L * 128 + ((((u << 2) | (kg * 2 + h)) ^ s) * 16);
    }
#pragma unroll
    for (int an = 0; an < 2; ++an) {
        const int r = wn * 64 + an * 32 + l31;
        const int L = r >> 1, u = r & 1, s = L & 7;
#pragma unroll
        for (int h = 0; h < 2; ++h)
            boff[an][h] = 8192 + L * 128 + ((((u << 2) | (kg * 2 + h)) ^ s) * 16);
    }

    f32x16 acc00 = {0.f}, acc01 = {0.f}, acc10 = {0.f}, acc11 = {0.f};
#pragma unroll
    for (int i = 0; i < 16; ++i) { acc00[i] = 0.f; acc01[i] = 0.f; acc10[i] = 0.f; acc11[i] = 0.f; }

    const int SCALE1 = 0x7F7F7F7F;   // E8M0 = 127 -> 2^0 per byte (unit scale)

#pragma unroll
    for (int t = 0; t < NKT; ++t) {
        const char* bp = &buf[t % 3][0];
        if (t + 2 < NKT) stage(t + 2, (t + 2) % 3);

        const i32x4 a0l = *reinterpret_cast<const i32x4*>(bp + aoff[0][0]);
        const i32x4 a0h = *reinterpret_cast<const i32x4*>(bp + aoff[0][1]);
        const i32x4 a1l = *reinterpret_cast<const i32x4*>(bp + aoff[1][0]);
        const i32x4 a1h = *reinterpret_cast<const i32x4*>(bp + aoff[1][1]);
        const i32x4 b0l = *reinterpret_cast<const i32x4*>(bp + boff[0][0]);
        const i32x4 b0h = *reinterpret_cast<const i32x4*>(bp + boff[0][1]);
        const i32x4 b1l = *reinterpret_cast<const i32x4*>(bp + boff[1][0]);
        const i32x4 b1h = *reinterpret_cast<const i32x4*>(bp + boff[1][1]);

        const i32x8 A0 = __builtin_shufflevector(a0l, a0h, 0, 1, 2, 3, 4, 5, 6, 7);
        const i32x8 A1 = __builtin_shufflevector(a1l, a1h, 0, 1, 2, 3, 4, 5, 6, 7);
        const i32x8 B0 = __builtin_shufflevector(b0l, b0h, 0, 1, 2, 3, 4, 5, 6, 7);
        const i32x8 B1 = __builtin_shufflevector(b1l, b1h, 0, 1, 2, 3, 4, 5, 6, 7);

        __builtin_amdgcn_s_setprio(1);
        acc00 = __builtin_amdgcn_mfma_scale_f32_32x32x64_f8f6f4(
            A0, B0, acc00, 0, 0, 0, SCALE1, 0, SCALE1);
        acc01 = __builtin_amdgcn_mfma_scale_f32_32x32x64_f8f6f4(
            A0, B1, acc01, 0, 0, 0, SCALE1, 0, SCALE1);
        acc10 = __builtin_amdgcn_mfma_scale_f32_32x32x64_f8f6f4(
            A1, B0, acc10, 0, 0, 0, SCALE1, 0, SCALE1);
        acc11 = __builtin_amdgcn_mfma_scale_f32_32x32x64_f8f6f4(
            A1, B1, acc11, 0, 0, 0, SCALE1, 0, SCALE1);
        __builtin_amdgcn_s_setprio(0);

        // end of tile: my ds_reads retired; tile t+1's DMAs landed; t+2 flying
        asm volatile("s_waitcnt lgkmcnt(0)" ::: "memory");
        if (t < NKT - 2)       asm volatile("s_waitcnt vmcnt(4)" ::: "memory");
        else if (t == NKT - 2) asm volatile("s_waitcnt vmcnt(0)" ::: "memory");
        __builtin_amdgcn_s_barrier();
    }

    // ---- epilogue: per-row max (diag excluded, scaled x128*sgn) + own ----
    // C/D 32x32 layout: col = n0 + wn*64 + an*32 + l31,
    //                   row = wm*64 + am*32 + (reg&3) + 8*(reg>>2) + 4*kg.
    const float NEG = -1e30f;
#pragma unroll
    for (int am = 0; am < 2; ++am) {
#pragma unroll
        for (int reg = 0; reg < 16; ++reg) {
            const int rl  = wm * 64 + am * 32 + (reg & 3) + 8 * (reg >> 2) + 4 * kg;
            const int spk = (r0 + rl) >> 5;
            float m = NEG, o = NEG;
            {
                const int col0 = n0 + wn * 64 + l31;          // an = 0
                const float v0 = am ? acc10[reg] : acc00[reg];
                const bool dg0 = (col0 == spk);
                o = dg0 ? v0 : o;
                m = fmaxf(m, dg0 ? NEG : v0);
                const int col1 = col0 + 32;                   // an = 1
                const float v1 = am ? acc11[reg] : acc01[reg];
                const bool dg1 = (col1 == spk);
                o = dg1 ? v1 : o;
                m = fmaxf(m, dg1 ? NEG : v1);
            }
#pragma unroll
            for (int mask = 1; mask < 32; mask <<= 1) {
                m = fmaxf(m, __shfl_xor(m, mask));
                o = fmaxf(o, __shfl_xor(o, mask));
            }
            if (l31 == 0) {
                redm[wn][rl] = m;
                redo[wn][rl] = o;
            }
        }
    }
    __syncthreads();

    if (tid < 128) {
        const float mo = fmaxf(redm[0][tid], redm[1][tid]);
        maxo_part[(size_t)nt * NROWS + r0 + tid] = mo;
        if (nt == (mt >> 5)) {
            own_part[r0 + tid] = fmaxf(redo[0][tid], redo[1][tid]);
        }
    }
}

// ---- k3: per-row finish: combine 8 tile-maxes, sigmoid, loss/corr ----------
__global__ void __launch_bounds__(256) rowred_kernel(const float* __restrict__ maxo_part,
                                                     const float* __restrict__ own_part,
                                                     const float* __restrict__ lnw,
                                                     const float* __restrict__ lnb,
                                                     float* __restrict__ partsum) {
    const int r = blockIdx.x * 256 + threadIdx.x;
    const float lw = lnw[0], lb = lnb[0];
    const float sgn = (lw >= 0.f) ? 1.f : -1.f;
    const float alw = fabsf(lw);
    const float inv128 = 1.f / 128.f;

    float mo = maxo_part[r];
#pragma unroll
    for (int p = 1; p < NTILES; ++p)
        mo = fmaxf(mo, maxo_part[(size_t)p * NROWS + r]);
    const float O     = own_part[r];              // 128*sgn*(e.ck_own)
    const float t_own = sgn * O * inv128;
    const float ex    = (32.f * t_own - 1.f) * (1.f / 31.f);
    const float own_s = sigmoidf(lw * ex + lb);
    const float mo_s  = sigmoidf(alw * mo * inv128 + lb);
    float loss = 1.f - own_s + mo_s;
    float corr = (sgn * ex >= mo * inv128) ? 1.f : 0.f;

#pragma unroll
    for (int mask = 1; mask < 64; mask <<= 1) {
        loss += __shfl_xor(loss, mask);
        corr += __shfl_xor(corr, mask);
    }
    __shared__ float sl[4], sc[4];
    const int wv = threadIdx.x >> 6;
    if ((threadIdx.x & 63) == 0) { sl[wv] = loss; sc[wv] = corr; }
    __syncthreads();
    if (threadIdx.x == 0) {
        partsum[blockIdx.x]       = sl[0] + sl[1] + sl[2] + sl[3];
        partsum[128 + blockIdx.x] = sc[0] + sc[1] + sc[2] + sc[3];
    }
}

// ---- k4: final scalar reduce ----------------------------------------------
__global__ void __launch_bounds__(128) final_kernel(const float* __restrict__ partsum,
                                                    float* __restrict__ out) {
    const int t = threadIdx.x;
    float l = partsum[t];
    float c = partsum[128 + t];
#pragma unroll
    for (int mask = 1; mask < 64; mask <<= 1) {
        l += __shfl_xor(l, mask);
        c += __shfl_xor(c, mask);
    }
    __shared__ float sl[2], sc[2];
    if ((t & 63) == 0) { sl[t >> 6] = l; sc[t >> 6] = c; }
    __syncthreads();
    if (t == 0) {
        out[0] = (sl[0] + sl[1]) * (1.f / (float)NROWS);
        out[1] = (sc[0] + sc[1]) * (1.f / (float)NROWS);
    }
}

extern "C" void kernel_launch(void* const* d_in, const int* in_sizes, int n_in,
                              void* d_out, int out_size, void* d_ws, size_t ws_size,
                              hipStream_t stream) {
    (void)in_sizes; (void)n_in; (void)out_size; (void)ws_size;
    const float* emb = (const float*)d_in[0];
    const float* lnw = (const float*)d_in[3];
    const float* lnb = (const float*)d_in[4];
    float* out = (float*)d_out;

    char* ws = (char*)d_ws;
    char* e8  = ws;                                           // 16 MB
    char* ck8 = ws + (size_t)NROWS * D_DIM;                   // 512 KB
    float* maxo_part = (float*)(ck8 + (size_t)N_SPK * D_DIM); // 1 MB
    float* own_part  = (float*)((char*)maxo_part + (size_t)NTILES * NROWS * 4); // 128 KB
    float* partsum   = (float*)((char*)own_part + (size_t)NROWS * 4);           // 1 KB

    prep_kernel<<<N_SPK, 256, 0, stream>>>(emb, lnw, (unsigned int*)e8, (unsigned int*)ck8);
    gemm_kernel<<<NWG, 256, 0, stream>>>(e8, ck8, maxo_part, own_part);
    rowred_kernel<<<NROWS / 256, 256, 0, stream>>>(maxo_part, own_part, lnw, lnb, partsum);
    final_kernel<<<1, 128, 0, stream>>>(partsum, out);
}

// Round 14
// 75.942 us; speedup vs baseline: 1.4819x; 1.4819x over previous
//
#include <hip/hip_runtime.h>

// GE2E loss, N=1024 spk, M=32 utt, D=512.
// v14: MX-scaled fp8 GEMM retry (mfma_scale_f32_32x32x64_f8f6f4, unit E8M0
// scales = bit-identical to plain fp8, 2x rate; r13 proved correctness).
// Fixes vs r13: (1) h-segregated XOR LDS layout -> each fragment b128 covers
// 8 full lines (r12's measured-0-conflict profile); (2) register diet:
// unroll-1 K-loop, union operand assembly (no shufflevector) -> >=2 blocks/CU.
// prep r11-verbatim (linear e8/ck8). Ring-3 + counted vmcnt(4) per K-tile.
// sims scaled x128*sgn; /128 folded into rowred.

#define N_SPK 1024
#define M_UTT 32
#define D_DIM 512
#define NROWS (N_SPK * M_UTT)   // 32768
#define NTILES 8                // 1024/128 col tiles
#define MTILES 256              // 32768/128 row tiles
#define NWG (MTILES * NTILES)   // 2048
#define NKT 8                   // 512/64

typedef __attribute__((ext_vector_type(16))) float f32x16;
typedef __attribute__((ext_vector_type(8)))  int   i32x8;
typedef __attribute__((ext_vector_type(4)))  int   i32x4;

__device__ __forceinline__ void gload_lds16(const void* g, void* l) {
    __builtin_amdgcn_global_load_lds(
        (const __attribute__((address_space(1))) unsigned int*)g,
        (__attribute__((address_space(3))) unsigned int*)l, 16, 0, 0);
}

__device__ __forceinline__ float sigmoidf(float x) {
    return 1.f / (1.f + __expf(-x));
}

// ---- k1: e8 = fp8(8*emb), ck8 = fp8(16*sgn(lw)*ck), linear (r11-verbatim) --
__global__ void __launch_bounds__(256) prep_kernel(const float* __restrict__ emb,
                                                   const float* __restrict__ lnw,
                                                   unsigned int* __restrict__ e8,
                                                   unsigned int* __restrict__ ck8) {
    __shared__ float part[2][D_DIM];
    const int n = blockIdx.x;
    const int t = threadIdx.x;
    const int d4 = (t & 127) * 4;
    const int mh = t >> 7;
    const float* base = emb + (size_t)n * M_UTT * D_DIM;

    float4 acc = {0.f, 0.f, 0.f, 0.f};
#pragma unroll
    for (int mm = 0; mm < 16; ++mm) {
        const int m = mh * 16 + mm;
        const float4 v = *reinterpret_cast<const float4*>(base + m * D_DIM + d4);
        acc.x += v.x; acc.y += v.y; acc.z += v.z; acc.w += v.w;
        int w = __builtin_amdgcn_cvt_pk_fp8_f32(8.f * v.x, 8.f * v.y, 0, false);
        w = __builtin_amdgcn_cvt_pk_fp8_f32(8.f * v.z, 8.f * v.w, w, true);
        e8[(((size_t)(n * M_UTT + m)) * D_DIM + d4) >> 2] = (unsigned int)w;
    }
    *reinterpret_cast<float4*>(&part[mh][d4]) = acc;
    __syncthreads();
    if (t < 128) {
        const float sgn = (lnw[0] >= 0.f) ? 1.f : -1.f;
        const float sc = sgn * 0.5f;   // 16*sgn*(sum/32)
        const int d = t * 4;
        const float4 a = *reinterpret_cast<const float4*>(&part[0][d]);
        const float4 b = *reinterpret_cast<const float4*>(&part[1][d]);
        int w = __builtin_amdgcn_cvt_pk_fp8_f32((a.x + b.x) * sc, (a.y + b.y) * sc, 0, false);
        w = __builtin_amdgcn_cvt_pk_fp8_f32((a.z + b.z) * sc, (a.w + b.w) * sc, w, true);
        ck8[(((size_t)n) * D_DIM + d) >> 2] = (unsigned int)w;
    }
}

// ---- k2: MX-fp8 GEMM, 128x128 blocks, ring-3, h-segregated LDS -------------
__global__ void __launch_bounds__(256)
gemm_kernel(const char* __restrict__ e8,
            const char* __restrict__ ck8,
            float* __restrict__ maxo_part,
            float* __restrict__ own_part) {
    // buf[slot] (16 KB): A region [0,8192), B region [8192,16384).
    // Region = 2 h-subregions of 4 KB. halfrow H = row*2 + kg (kg = 32B k-half)
    // stored at line = H>>3, phys slot = (H&7) ^ (line&7); chunk = 16B.
    // Source chunk (row, c=k/16): H = row*2 + (c>>1), h = c&1.
    __shared__ __align__(16) char buf[3][16384];   // 48 KB
    __shared__ float redm[2][128];
    __shared__ float redo[2][128];

    const int tid  = threadIdx.x;
    const int lane = tid & 63;
    const int wv   = tid >> 6;
    const int l31  = lane & 31;
    const int kg   = lane >> 5;    // k-half (32 bytes)
    const int wm   = wv >> 1;      // 0..1 : 64-row half
    const int wn   = wv & 1;       // 0..1 : 64-col half

    // XCD map (r12-verbatim): xcd gets 32 consecutive mt x all 8 nt
    const int raw   = blockIdx.x;
    const int xcd   = raw & 7;
    const int local = raw >> 3;              // 0..255
    const int mt    = xcd * 32 + (local >> 3);
    const int nt    = local & 7;
    const int r0    = mt * 128;
    const int n0    = nt * 128;

    // ---- staging map: dest chunk d in {tid, tid+256} per region ----
    const char* pA[2];
    const char* pB[2];
    int dA[2], dB[2];
#pragma unroll
    for (int j = 0; j < 2; ++j) {
        const int d    = j * 256 + tid;
        const int h    = d >> 8;
        const int p    = d & 255;
        const int line = p >> 3;
        const int slot = (p & 7) ^ (line & 7);
        const int H    = line * 8 + slot;
        const int row  = H >> 1;
        const int c    = (H & 1) * 2 + h;
        pA[j] = e8  + (size_t)(r0 + row) * D_DIM + c * 16;
        pB[j] = ck8 + (size_t)(n0 + row) * D_DIM + c * 16;
        dA[j] = d * 16;
        dB[j] = 8192 + d * 16;
    }

    auto stage = [&](int u, int slot) {
        char* bb = &buf[slot][0];
        const int ko = u * 64;
#pragma unroll
        for (int j = 0; j < 2; ++j) {
            gload_lds16(pA[j] + ko, bb + dA[j]);
            gload_lds16(pB[j] + ko, bb + dB[j]);
        }
    };

    // prologue: tiles 0,1 in flight; gate tile 0 only
    stage(0, 0);
    stage(1, 1);
    asm volatile("s_waitcnt vmcnt(4)" ::: "memory");
    __builtin_amdgcn_s_barrier();

    // ---- fragment read bases: hh = halfrow index within 64-group ----
    const int hh     = (l31 << 1) | kg;
    const int base_l = (hh >> 3) * 128 + (((hh & 7) ^ (hh >> 3)) * 16);
    const int aoff   = wm * 2048 + base_l;          // + am*1024 + h*4096
    const int boff   = 8192 + wn * 2048 + base_l;   // + an*1024 + h*4096

    f32x16 acc00, acc01, acc10, acc11;
#pragma unroll
    for (int i = 0; i < 16; ++i) { acc00[i] = 0.f; acc01[i] = 0.f; acc10[i] = 0.f; acc11[i] = 0.f; }

    const int SCALE1 = 0x7F7F7F7F;   // E8M0 127 = 2^0 per byte (unit scales)

    union Op { i32x8 v; struct { i32x4 lo, hi; } s; };

#pragma unroll 1
    for (int t = 0; t < NKT; ++t) {
        const char* bp = &buf[t % 3][0];
        if (t + 2 < NKT) stage(t + 2, (t + 2) % 3);

        Op A0, A1, B0, B1;
        A0.s.lo = *reinterpret_cast<const i32x4*>(bp + aoff);
        A0.s.hi = *reinterpret_cast<const i32x4*>(bp + aoff + 4096);
        A1.s.lo = *reinterpret_cast<const i32x4*>(bp + aoff + 1024);
        A1.s.hi = *reinterpret_cast<const i32x4*>(bp + aoff + 1024 + 4096);
        B0.s.lo = *reinterpret_cast<const i32x4*>(bp + boff);
        B0.s.hi = *reinterpret_cast<const i32x4*>(bp + boff + 4096);
        B1.s.lo = *reinterpret_cast<const i32x4*>(bp + boff + 1024);
        B1.s.hi = *reinterpret_cast<const i32x4*>(bp + boff + 1024 + 4096);

        __builtin_amdgcn_s_setprio(1);
        acc00 = __builtin_amdgcn_mfma_scale_f32_32x32x64_f8f6f4(
            A0.v, B0.v, acc00, 0, 0, 0, SCALE1, 0, SCALE1);
        acc01 = __builtin_amdgcn_mfma_scale_f32_32x32x64_f8f6f4(
            A0.v, B1.v, acc01, 0, 0, 0, SCALE1, 0, SCALE1);
        acc10 = __builtin_amdgcn_mfma_scale_f32_32x32x64_f8f6f4(
            A1.v, B0.v, acc10, 0, 0, 0, SCALE1, 0, SCALE1);
        acc11 = __builtin_amdgcn_mfma_scale_f32_32x32x64_f8f6f4(
            A1.v, B1.v, acc11, 0, 0, 0, SCALE1, 0, SCALE1);
        __builtin_amdgcn_s_setprio(0);

        // end of tile: my ds_reads retired; tile t+1's DMAs landed; t+2 flying
        asm volatile("s_waitcnt lgkmcnt(0)" ::: "memory");
        if (t < NKT - 2)       asm volatile("s_waitcnt vmcnt(4)" ::: "memory");
        else if (t == NKT - 2) asm volatile("s_waitcnt vmcnt(0)" ::: "memory");
        __builtin_amdgcn_s_barrier();
    }

    // ---- epilogue: per-row max (diag excluded, scaled x128*sgn) + own ----
    // C/D 32x32: col = n0 + wn*64 + an*32 + l31,
    //            row = wm*64 + am*32 + (reg&3) + 8*(reg>>2) + 4*kg  [m74/m101]
    const float NEG = -1e30f;
#pragma unroll
    for (int am = 0; am < 2; ++am) {
#pragma unroll
        for (int reg = 0; reg < 16; ++reg) {
            const int rl  = wm * 64 + am * 32 + (reg & 3) + 8 * (reg >> 2) + 4 * kg;
            const int spk = (r0 + rl) >> 5;
            float m = NEG, o = NEG;
            {
                const int col0 = n0 + wn * 64 + l31;          // an = 0
                const float v0 = am ? acc10[reg] : acc00[reg];
                const bool dg0 = (col0 == spk);
                o = dg0 ? v0 : o;
                m = fmaxf(m, dg0 ? NEG : v0);
                const int col1 = col0 + 32;                   // an = 1
                const float v1 = am ? acc11[reg] : acc01[reg];
                const bool dg1 = (col1 == spk);
                o = dg1 ? v1 : o;
                m = fmaxf(m, dg1 ? NEG : v1);
            }
#pragma unroll
            for (int mask = 1; mask < 32; mask <<= 1) {
                m = fmaxf(m, __shfl_xor(m, mask));
                o = fmaxf(o, __shfl_xor(o, mask));
            }
            if (l31 == 0) {
                redm[wn][rl] = m;
                redo[wn][rl] = o;
            }
        }
    }
    __syncthreads();

    if (tid < 128) {
        const float mo = fmaxf(redm[0][tid], redm[1][tid]);
        maxo_part[(size_t)nt * NROWS + r0 + tid] = mo;
        if (nt == (mt >> 5)) {
            own_part[r0 + tid] = fmaxf(redo[0][tid], redo[1][tid]);
        }
    }
}

// ---- k3: per-row finish: combine 8 tile-maxes, sigmoid, loss/corr ----------
__global__ void __launch_bounds__(256) rowred_kernel(const float* __restrict__ maxo_part,
                                                     const float* __restrict__ own_part,
                                                     const float* __restrict__ lnw,
                                                     const float* __restrict__ lnb,
                                                     float* __restrict__ partsum) {
    const int r = blockIdx.x * 256 + threadIdx.x;
    const float lw = lnw[0], lb = lnb[0];
    const float sgn = (lw >= 0.f) ? 1.f : -1.f;
    const float alw = fabsf(lw);
    const float inv128 = 1.f / 128.f;

    float mo = maxo_part[r];
#pragma unroll
    for (int p = 1; p < NTILES; ++p)
        mo = fmaxf(mo, maxo_part[(size_t)p * NROWS + r]);
    const float O     = own_part[r];              // 128*sgn*(e.ck_own)
    const float t_own = sgn * O * inv128;
    const float ex    = (32.f * t_own - 1.f) * (1.f / 31.f);
    const float own_s = sigmoidf(lw * ex + lb);
    const float mo_s  = sigmoidf(alw * mo * inv128 + lb);
    float loss = 1.f - own_s + mo_s;
    float corr = (sgn * ex >= mo * inv128) ? 1.f : 0.f;

#pragma unroll
    for (int mask = 1; mask < 64; mask <<= 1) {
        loss += __shfl_xor(loss, mask);
        corr += __shfl_xor(corr, mask);
    }
    __shared__ float sl[4], sc[4];
    const int wv = threadIdx.x >> 6;
    if ((threadIdx.x & 63) == 0) { sl[wv] = loss; sc[wv] = corr; }
    __syncthreads();
    if (threadIdx.x == 0) {
        partsum[blockIdx.x]       = sl[0] + sl[1] + sl[2] + sl[3];
        partsum[128 + blockIdx.x] = sc[0] + sc[1] + sc[2] + sc[3];
    }
}

// ---- k4: final scalar reduce ----------------------------------------------
__global__ void __launch_bounds__(128) final_kernel(const float* __restrict__ partsum,
                                                    float* __restrict__ out) {
    const int t = threadIdx.x;
    float l = partsum[t];
    float c = partsum[128 + t];
#pragma unroll
    for (int mask = 1; mask < 64; mask <<= 1) {
        l += __shfl_xor(l, mask);
        c += __shfl_xor(c, mask);
    }
    __shared__ float sl[2], sc[2];
    if ((t & 63) == 0) { sl[t >> 6] = l; sc[t >> 6] = c; }
    __syncthreads();
    if (t == 0) {
        out[0] = (sl[0] + sl[1]) * (1.f / (float)NROWS);
        out[1] = (sc[0] + sc[1]) * (1.f / (float)NROWS);
    }
}

extern "C" void kernel_launch(void* const* d_in, const int* in_sizes, int n_in,
                              void* d_out, int out_size, void* d_ws, size_t ws_size,
                              hipStream_t stream) {
    (void)in_sizes; (void)n_in; (void)out_size; (void)ws_size;
    const float* emb = (const float*)d_in[0];
    const float* lnw = (const float*)d_in[3];
    const float* lnb = (const float*)d_in[4];
    float* out = (float*)d_out;

    char* ws = (char*)d_ws;
    char* e8  = ws;                                           // 16 MB
    char* ck8 = ws + (size_t)NROWS * D_DIM;                   // 512 KB
    float* maxo_part = (float*)(ck8 + (size_t)N_SPK * D_DIM); // 1 MB
    float* own_part  = (float*)((char*)maxo_part + (size_t)NTILES * NROWS * 4); // 128 KB
    float* partsum   = (float*)((char*)own_part + (size_t)NROWS * 4);           // 1 KB

    prep_kernel<<<N_SPK, 256, 0, stream>>>(emb, lnw, (unsigned int*)e8, (unsigned int*)ck8);
    gemm_kernel<<<NWG, 256, 0, stream>>>(e8, ck8, maxo_part, own_part);
    rowred_kernel<<<NROWS / 256, 256, 0, stream>>>(maxo_part, own_part, lnw, lnb, partsum);
    final_kernel<<<1, 128, 0, stream>>>(partsum, out);
}

// Round 15
// 55.292 us; speedup vs baseline: 2.0353x; 1.3735x over previous
//
#include <hip/hip_runtime.h>

// GE2E loss, N=1024 spk, M=32 utt, D=512.
// v15 = r12 gemm (39.8us, 0 bank conflicts, 863 TF-eq) + r11-speed prep.
// prep: e8 = fp8(8*emb), ck8 = fp8(16*sgn(lw)*ck), stored K-PERMUTED:
//   byte k -> (k&~63) + ((k>>3)&3)*16 + ((k>>5)&1)*8 + (k&7)
// applied as a store-offset remap only (4B packed stores as in r11).
// gemm: 2048 blocks of 128x128, 4 waves; LDS ring-3 x 16 KB; stage(t+2) at
// tile start via global_load_lds (pre-swizzled source); 1 barrier + counted
// vmcnt(4) per K-tile; fragment = 1 ds_read_b128 (r12 measured-0-conflict
// pattern) feeding two K=32 fp8 MFMAs. sims scaled x128*sgn; /128 in rowred.

#define N_SPK 1024
#define M_UTT 32
#define D_DIM 512
#define NROWS (N_SPK * M_UTT)   // 32768
#define NTILES 8                // 1024/128 col tiles
#define MTILES 256              // 32768/128 row tiles
#define NWG (MTILES * NTILES)   // 2048
#define NKT 8                   // 512/64

typedef __attribute__((ext_vector_type(4))) float f32x4;
typedef __attribute__((ext_vector_type(2))) long long2v;   // 16 B

__device__ __forceinline__ void gload_lds16(const void* g, void* l) {
    __builtin_amdgcn_global_load_lds(
        (const __attribute__((address_space(1))) unsigned int*)g,
        (__attribute__((address_space(3))) unsigned int*)l, 16, 0, 0);
}

__device__ __forceinline__ float sigmoidf(float x) {
    return 1.f / (1.f + __expf(-x));
}

// ---- k1: e8 = fp8(8*emb), ck8 = fp8(16*sgn(lw)*ck), permuted stores --------
__global__ void __launch_bounds__(256) prep_kernel(const float* __restrict__ emb,
                                                   const float* __restrict__ lnw,
                                                   unsigned int* __restrict__ e8,
                                                   unsigned int* __restrict__ ck8) {
    __shared__ float part[2][D_DIM];
    const int n = blockIdx.x;
    const int t = threadIdx.x;
    const int d4 = (t & 127) * 4;
    const int mh = t >> 7;
    // permuted destination of the 4-byte group starting at k = d4
    const int od = (d4 & ~63) + ((d4 >> 3) & 3) * 16 + ((d4 >> 5) & 1) * 8 + (d4 & 4);
    const float* base = emb + (size_t)n * M_UTT * D_DIM;

    float4 acc = {0.f, 0.f, 0.f, 0.f};
#pragma unroll
    for (int mm = 0; mm < 16; ++mm) {
        const int m = mh * 16 + mm;
        const float4 v = *reinterpret_cast<const float4*>(base + m * D_DIM + d4);
        acc.x += v.x; acc.y += v.y; acc.z += v.z; acc.w += v.w;
        int w = __builtin_amdgcn_cvt_pk_fp8_f32(8.f * v.x, 8.f * v.y, 0, false);
        w = __builtin_amdgcn_cvt_pk_fp8_f32(8.f * v.z, 8.f * v.w, w, true);
        e8[(((size_t)(n * M_UTT + m)) * D_DIM + od) >> 2] = (unsigned int)w;
    }
    *reinterpret_cast<float4*>(&part[mh][d4]) = acc;
    __syncthreads();
    if (t < 128) {
        const float sgn = (lnw[0] >= 0.f) ? 1.f : -1.f;
        const float sc = sgn * 0.5f;   // 16*sgn*(sum/32)
        const int d = t * 4;
        const int odc = (d & ~63) + ((d >> 3) & 3) * 16 + ((d >> 5) & 1) * 8 + (d & 4);
        const float4 a = *reinterpret_cast<const float4*>(&part[0][d]);
        const float4 b = *reinterpret_cast<const float4*>(&part[1][d]);
        int w = __builtin_amdgcn_cvt_pk_fp8_f32((a.x + b.x) * sc, (a.y + b.y) * sc, 0, false);
        w = __builtin_amdgcn_cvt_pk_fp8_f32((a.z + b.z) * sc, (a.w + b.w) * sc, w, true);
        ck8[(((size_t)n) * D_DIM + odc) >> 2] = (unsigned int)w;
    }
}

// ---- k2: fp8 GEMM, 128x128 blocks, ring-3, counted vmcnt (r12-verbatim) ----
__global__ void __launch_bounds__(256, 3)
gemm_kernel(const char* __restrict__ e8,
            const char* __restrict__ ck8,
            float* __restrict__ maxo_part,
            float* __restrict__ own_part) {
    // buf[slot]: A 128x64B at [0,8192), B at [8192,16384).
    // line L (128B) = rows {2L,2L+1}; logical chunk l = (row&1)*4 + c,
    // stored at phys = l ^ (L&7). Chunk c of a row = {kk0 octet c, kk1 octet c}
    // (from the prep permutation).
    __shared__ __align__(16) char buf[3][16384];   // 48 KB
    __shared__ float redm[2][128];
    __shared__ float redo[2][128];

    const int tid  = threadIdx.x;
    const int lane = tid & 63;
    const int wv   = tid >> 6;
    const int lo   = lane & 15;
    const int hi   = lane >> 4;
    const int wm   = wv >> 1;   // 0..1 : 64-row half
    const int wn   = wv & 1;    // 0..1 : 64-col half

    // XCD map: xcd gets 32 consecutive mt x all 8 nt (A 2MB + ck 0.5MB in L2)
    const int raw   = blockIdx.x;
    const int xcd   = raw & 7;
    const int local = raw >> 3;              // 0..255
    const int mt    = xcd * 32 + (local >> 3);
    const int nt    = local & 7;
    const int r0    = mt * 128;
    const int n0    = nt * 128;

    // ---- staging map: 512 16B-chunks per region, 2 per thread ----
    const char* pA[2];
    const char* pB[2];
    int dA[2], dB[2];
#pragma unroll
    for (int j = 0; j < 2; ++j) {
        const int s   = j * 256 + tid;
        const int L   = s >> 3;
        const int l   = (s & 7) ^ (L & 7);
        const int row = 2 * L + (l >> 2);
        const int c   = l & 3;
        pA[j] = e8  + (size_t)(r0 + row) * D_DIM + c * 16;
        pB[j] = ck8 + (size_t)(n0 + row) * D_DIM + c * 16;
        dA[j] = s * 16;
        dB[j] = 8192 + s * 16;
    }

    auto stage = [&](int u, int slot) {
        char* bb = &buf[slot][0];
        const int ko = u * 64;
#pragma unroll
        for (int j = 0; j < 2; ++j) {
            gload_lds16(pA[j] + ko, bb + dA[j]);
            gload_lds16(pB[j] + ko, bb + dB[j]);
        }
    };

    // prologue: tiles 0,1 in flight; gate tile 0 only
    stage(0, 0);
    stage(1, 1);
    asm volatile("s_waitcnt vmcnt(4)" ::: "memory");
    __builtin_amdgcn_s_barrier();

    // ---- fragment read addressing (one b128 per frag, r12 0-conflict) ----
    const int swz   = (lo >> 1) & 7;
    const int par   = lo & 1;
    const int physr = ((par << 2) | hi) ^ swz;
    const int abase = (wm * 32 + (lo >> 1)) * 128 + physr * 16;
    const int bbase = 8192 + (wn * 32 + (lo >> 1)) * 128 + physr * 16;

    f32x4 acc[4][4];
#pragma unroll
    for (int am = 0; am < 4; ++am)
#pragma unroll
        for (int an = 0; an < 4; ++an) acc[am][an] = (f32x4){0.f, 0.f, 0.f, 0.f};

#pragma unroll
    for (int t = 0; t < NKT; ++t) {
        const char* bp = &buf[t % 3][0];
        if (t + 2 < NKT) stage(t + 2, (t + 2) % 3);

        long2v a2[4], b2[4];
#pragma unroll
        for (int am = 0; am < 4; ++am)
            a2[am] = *reinterpret_cast<const long2v*>(bp + abase + am * 1024);
#pragma unroll
        for (int an = 0; an < 4; ++an)
            b2[an] = *reinterpret_cast<const long2v*>(bp + bbase + an * 1024);

        __builtin_amdgcn_s_setprio(1);
#pragma unroll
        for (int am = 0; am < 4; ++am)
#pragma unroll
            for (int an = 0; an < 4; ++an)
                acc[am][an] = __builtin_amdgcn_mfma_f32_16x16x32_fp8_fp8(
                    a2[am][0], b2[an][0], acc[am][an], 0, 0, 0);
#pragma unroll
        for (int am = 0; am < 4; ++am)
#pragma unroll
            for (int an = 0; an < 4; ++an)
                acc[am][an] = __builtin_amdgcn_mfma_f32_16x16x32_fp8_fp8(
                    a2[am][1], b2[an][1], acc[am][an], 0, 0, 0);
        __builtin_amdgcn_s_setprio(0);

        // end of tile: my ds_reads retired; tile t+1's DMAs (issued at t-1)
        // landed; t+2's batch (just issued) stays in flight.
        asm volatile("s_waitcnt lgkmcnt(0)" ::: "memory");
        if (t < NKT - 2)       asm volatile("s_waitcnt vmcnt(4)" ::: "memory");
        else if (t == NKT - 2) asm volatile("s_waitcnt vmcnt(0)" ::: "memory");
        __builtin_amdgcn_s_barrier();
    }

    // ---- epilogue: per-row max (diag excluded, scaled x128*sgn) + own ----
    const float NEG = -1e30f;
#pragma unroll
    for (int am = 0; am < 4; ++am) {
#pragma unroll
        for (int reg = 0; reg < 4; ++reg) {
            const int rl   = wm * 64 + am * 16 + hi * 4 + reg;
            const int rowg = r0 + rl;
            const int spk  = rowg >> 5;
            float m = NEG, o = NEG;
#pragma unroll
            for (int an = 0; an < 4; ++an) {
                const int col = n0 + wn * 64 + an * 16 + lo;
                const float v = acc[am][an][reg];
                const bool dg = (col == spk);
                o = dg ? v : o;
                m = fmaxf(m, dg ? NEG : v);
            }
#pragma unroll
            for (int mask = 1; mask < 16; mask <<= 1) {
                m = fmaxf(m, __shfl_xor(m, mask));
                o = fmaxf(o, __shfl_xor(o, mask));
            }
            if (lo == 0) {
                redm[wn][rl] = m;
                redo[wn][rl] = o;
            }
        }
    }
    __syncthreads();

    if (tid < 128) {
        const float mo = fmaxf(redm[0][tid], redm[1][tid]);
        maxo_part[(size_t)nt * NROWS + r0 + tid] = mo;
        if (nt == (mt >> 5)) {
            own_part[r0 + tid] = fmaxf(redo[0][tid], redo[1][tid]);
        }
    }
}

// ---- k3: per-row finish: combine 8 tile-maxes, sigmoid, loss/corr ----------
__global__ void __launch_bounds__(256) rowred_kernel(const float* __restrict__ maxo_part,
                                                     const float* __restrict__ own_part,
                                                     const float* __restrict__ lnw,
                                                     const float* __restrict__ lnb,
                                                     float* __restrict__ partsum) {
    const int r = blockIdx.x * 256 + threadIdx.x;
    const float lw = lnw[0], lb = lnb[0];
    const float sgn = (lw >= 0.f) ? 1.f : -1.f;
    const float alw = fabsf(lw);
    const float inv128 = 1.f / 128.f;

    float mo = maxo_part[r];
#pragma unroll
    for (int p = 1; p < NTILES; ++p)
        mo = fmaxf(mo, maxo_part[(size_t)p * NROWS + r]);
    const float O     = own_part[r];              // 128*sgn*(e.ck_own)
    const float t_own = sgn * O * inv128;
    const float ex    = (32.f * t_own - 1.f) * (1.f / 31.f);
    const float own_s = sigmoidf(lw * ex + lb);
    const float mo_s  = sigmoidf(alw * mo * inv128 + lb);
    float loss = 1.f - own_s + mo_s;
    float corr = (sgn * ex >= mo * inv128) ? 1.f : 0.f;

#pragma unroll
    for (int mask = 1; mask < 64; mask <<= 1) {
        loss += __shfl_xor(loss, mask);
        corr += __shfl_xor(corr, mask);
    }
    __shared__ float sl[4], sc[4];
    const int wv = threadIdx.x >> 6;
    if ((threadIdx.x & 63) == 0) { sl[wv] = loss; sc[wv] = corr; }
    __syncthreads();
    if (threadIdx.x == 0) {
        partsum[blockIdx.x]       = sl[0] + sl[1] + sl[2] + sl[3];
        partsum[128 + blockIdx.x] = sc[0] + sc[1] + sc[2] + sc[3];
    }
}

// ---- k4: final scalar reduce ----------------------------------------------
__global__ void __launch_bounds__(128) final_kernel(const float* __restrict__ partsum,
                                                    float* __restrict__ out) {
    const int t = threadIdx.x;
    float l = partsum[t];
    float c = partsum[128 + t];
#pragma unroll
    for (int mask = 1; mask < 64; mask <<= 1) {
        l += __shfl_xor(l, mask);
        c += __shfl_xor(c, mask);
    }
    __shared__ float sl[2], sc[2];
    if ((t & 63) == 0) { sl[t >> 6] = l; sc[t >> 6] = c; }
    __syncthreads();
    if (t == 0) {
        out[0] = (sl[0] + sl[1]) * (1.f / (float)NROWS);
        out[1] = (sc[0] + sc[1]) * (1.f / (float)NROWS);
    }
}

extern "C" void kernel_launch(void* const* d_in, const int* in_sizes, int n_in,
                              void* d_out, int out_size, void* d_ws, size_t ws_size,
                              hipStream_t stream) {
    (void)in_sizes; (void)n_in; (void)out_size; (void)ws_size;
    const float* emb = (const float*)d_in[0];
    const float* lnw = (const float*)d_in[3];
    const float* lnb = (const float*)d_in[4];
    float* out = (float*)d_out;

    char* ws = (char*)d_ws;
    char* e8  = ws;                                           // 16 MB
    char* ck8 = ws + (size_t)NROWS * D_DIM;                   // 512 KB
    float* maxo_part = (float*)(ck8 + (size_t)N_SPK * D_DIM); // 1 MB
    float* own_part  = (float*)((char*)maxo_part + (size_t)NTILES * NROWS * 4); // 128 KB
    float* partsum   = (float*)((char*)own_part + (size_t)NROWS * 4);           // 1 KB

    prep_kernel<<<N_SPK, 256, 0, stream>>>(emb, lnw, (unsigned int*)e8, (unsigned int*)ck8);
    gemm_kernel<<<NWG, 256, 0, stream>>>(e8, ck8, maxo_part, own_part);
    rowred_kernel<<<NROWS / 256, 256, 0, stream>>>(maxo_part, own_part, lnw, lnb, partsum);
    final_kernel<<<1, 128, 0, stream>>>(partsum, out);
}